// Round 8
// baseline (95.872 us; speedup 1.0000x reference)
//
#include <hip/hip_runtime.h>
#include <hip/hip_fp16.h>

#define WIDTH   256
#define HEIGHT  256
#define NG      8192
#define TILE_SZ 16
#define MINW    1e-6f
#define BLK     1024
#define NBATCH  (NG / BLK)      // 8
#define NWAVE   (BLK / 64)      // 16
#define NSEG    16              // depth segments (one per wave)
#define RSZ     512             // gaussians staged per round
#define KC      (-0.72134752044f)   // -0.5 * log2(e)

// ---- Kernel 1: pack per-gaussian params + bbox once
__global__ __launch_bounds__(256) void prep_kernel(
    const float* __restrict__ pts, const float* __restrict__ icov,
    const float* __restrict__ cols, const float* __restrict__ opac,
    const float* __restrict__ rad,
    float4* __restrict__ table, float4* __restrict__ bbt)
{
    const int g = blockIdx.x * 256 + threadIdx.x;
    const float2 p = ((const float2*)pts)[g];
    const float4 ic = ((const float4*)icov)[g];
    const float r  = rad[g];
    const float op = 1.0f / (1.0f + __expf(-opac[g]));
    const __half2 h = __floats2half2_rn(cols[3 * g], cols[3 * g + 1]);
    unsigned rgbits; __builtin_memcpy(&rgbits, &h, 4);
    table[2 * g + 0] = make_float4(p.x, p.y, KC * ic.x, 2.0f * KC * ic.y);
    table[2 * g + 1] = make_float4(KC * ic.w, op, __uint_as_float(rgbits),
                                   cols[3 * g + 2]);
    bbt[g] = make_float4(floorf(p.x - r), ceilf(p.x + r),
                         floorf(p.y - r), ceilf(p.y + r));
}

// ---- Kernel 2: per-tile cull + depth-split composite (1 block per tile)
__global__ __launch_bounds__(BLK, 4) void raster_kernel(
    const float4* __restrict__ bbt,   // [N] bbox
    const float4* __restrict__ table, // [N,2] packed params
    float* __restrict__ out)          // [W,H,3]
{
    __shared__ unsigned long long s_ball[NBATCH * NWAVE];   // 1 KB
    __shared__ int s_pfx[NBATCH * NWAVE];                   // 0.5 KB
    __shared__ __align__(16) char s_pool[32768];            // 32 KB
    unsigned short* s_list = (unsigned short*)s_pool;       // 16 KB ordered ids
    float4* s_g = (float4*)(s_pool + 16384);                // 16 KB staged chunk
    __shared__ float s_P[NSEG][256];                        // 16 KB P / Tin / reduce

    const int tid  = threadIdx.x;
    const int lane = tid & 63;
    const int wave = tid >> 6;
    const int seg  = wave;            // 0..15
    const float tx0 = (float)(blockIdx.x * TILE_SZ);
    const float ty0 = (float)(blockIdx.y * TILE_SZ);
    const float tx1 = tx0 + (float)TILE_SZ;
    const float ty1 = ty0 + (float)TILE_SZ;

    // ---- Phase 1: prefetch all 8 bboxes, then ballot + wave-0 scan
    float4 bb[NBATCH];
    #pragma unroll
    for (int b = 0; b < NBATCH; ++b) bb[b] = bbt[b * BLK + tid];
    unsigned int hitbits = 0;
    #pragma unroll
    for (int b = 0; b < NBATCH; ++b) {
        bool hit = (bb[b].x <= tx1) & (bb[b].y >= tx0)
                 & (bb[b].z <= ty1) & (bb[b].w >= ty0);
        unsigned long long m = __ballot(hit);
        if (lane == 0) s_ball[b * NWAVE + wave] = m;
        if (hit) hitbits |= (1u << b);
    }
    __syncthreads();
    if (wave == 0) {                  // 128-elem inclusive scan in one wave
        int v0 = __popcll(s_ball[lane]);
        int v1 = __popcll(s_ball[64 + lane]);
        #pragma unroll
        for (int d = 1; d < 64; d <<= 1) {
            const int t0 = __shfl_up(v0, d);
            const int t1 = __shfl_up(v1, d);
            if (lane >= d) { v0 += t0; v1 += t1; }
        }
        s_pfx[lane] = v0;
        s_pfx[64 + lane] = v1 + __shfl(v0, 63);
    }
    __syncthreads();
    const int count = s_pfx[127];
    {
        unsigned int hb = hitbits;
        const unsigned long long ltmask = (1ull << lane) - 1ull;
        while (hb) {
            const int b = __ffs(hb) - 1;  hb &= hb - 1;
            const int idx = b * NWAVE + wave;
            const unsigned long long m = s_ball[idx];
            const int bs = idx ? s_pfx[idx - 1] : 0;
            s_list[bs + __popcll(m & ltmask)] = (unsigned short)(b * BLK + tid);
        }
    }
    __syncthreads();

    // ---- Phase 2: 16 depth segments x 64 quads (2x2 px per thread)
    const int q  = tid & 63;
    const int qx = q >> 3, qy = q & 7;
    const float fx = tx0 + (float)(2 * qx);   // pixel A x; B = +1
    const float fy = ty0 + (float)(2 * qy);   // pixel A y; B = +1
    // pixel indices (x-major, p = lx*16+ly): k0=(xa,ya) k1=(xa,yb) k2=(xb,ya) k3=(xb,yb)
    const int p0 = (2 * qx) * 16 + 2 * qy;
    const int pxi[4] = {p0, p0 + 1, p0 + 16, p0 + 17};
    float Tpx = 1.0f;                          // per-pixel T, owner threads (tid<256)
    float acc[3][4];
    #pragma unroll
    for (int c = 0; c < 3; ++c)
        #pragma unroll
        for (int k = 0; k < 4; ++k) acc[c][k] = 0.0f;

    for (int base = 0; base < count; base += RSZ) {
        const int n = min(RSZ, count - base);
        if (tid < n) {
            const int g = s_list[base + tid];
            s_g[tid * 2 + 0] = table[2 * g + 0];
            s_g[tid * 2 + 1] = table[2 * g + 1];
        }
        __syncthreads();

        const int L  = (n + NSEG - 1) >> 4;
        const int i0 = seg * L;
        const int i1 = min(i0 + L, n);

        float P[4] = {1.f, 1.f, 1.f, 1.f};
        float l[3][4];
        #pragma unroll
        for (int c = 0; c < 3; ++c)
            #pragma unroll
            for (int k = 0; k < 4; ++k) l[c][k] = 0.0f;

        #pragma unroll 2
        for (int i = i0; i < i1; ++i) {
            const float4 g0 = s_g[i * 2 + 0];
            const float4 g1 = s_g[i * 2 + 1];
            const float dya = fy - g0.y,  dyb = dya + 1.0f;
            const float dxa = fx - g0.x,  dxb = dxa + 1.0f;
            const float bya = g0.w * dya, byb = g0.w * dyb;
            const float cya = (g1.x * dya) * dya, cyb = (g1.x * dyb) * dyb;
            const float axa = (g0.z * dxa) * dxa, axb = (g0.z * dxb) * dxb;
            const unsigned rgbits = __float_as_uint(g1.z);
            __half2 h; __builtin_memcpy(&h, &rgbits, 4);
            const float2 rg = __half22float2(h);
            const float qv[4] = { fmaf(dxa, bya, axa + cya),
                                  fmaf(dxa, byb, axa + cyb),
                                  fmaf(dxb, bya, axb + cya),
                                  fmaf(dxb, byb, axb + cyb) };
            #pragma unroll
            for (int k = 0; k < 4; ++k) {
                const float a = g1.y * __builtin_amdgcn_exp2f(qv[k]);
                const float w = P[k] * a;
                l[0][k] = fmaf(w, rg.x, l[0][k]);
                l[1][k] = fmaf(w, rg.y, l[1][k]);
                l[2][k] = fmaf(w, g1.w, l[2][k]);
                P[k] = fmaf(-a, P[k], P[k]);
            }
        }
        #pragma unroll
        for (int k = 0; k < 4; ++k) s_P[seg][pxi[k]] = P[k];
        __syncthreads();

        // owner threads: in-place exclusive-prefix (Tin per segment) over 16 P's
        if (tid < 256) {
            float run = Tpx;
            #pragma unroll
            for (int s = 0; s < NSEG; ++s) {
                const float Pv = s_P[s][tid];
                s_P[s][tid] = run;            // Tin for segment s
                run *= Pv;
            }
            Tpx = run;                        // T after this round
        }
        __syncthreads();

        float Tin[4];
        bool gated[4]; bool anyg = false;
        #pragma unroll
        for (int k = 0; k < 4; ++k) {
            Tin[k] = s_P[seg][pxi[k]];
            const bool alive = (Tin[k] >= MINW);
            gated[k] = alive && (Tin[k] * P[k] < MINW);  // T crossed in this seg
            if (alive && !gated[k]) {
                acc[0][k] = fmaf(Tin[k], l[0][k], acc[0][k]);
                acc[1][k] = fmaf(Tin[k], l[1][k], acc[1][k]);
                acc[2][k] = fmaf(Tin[k], l[2][k], acc[2][k]);
            }
            anyg |= gated[k];
        }
        if (__ballot(anyg) != 0ull) {         // rare: once per pixel lifetime
            float Tl[4] = {Tin[0], Tin[1], Tin[2], Tin[3]};
            for (int i = i0; i < i1; ++i) {
                const float4 g0 = s_g[i * 2 + 0];
                const float4 g1 = s_g[i * 2 + 1];
                const float dya = fy - g0.y,  dyb = dya + 1.0f;
                const float dxa = fx - g0.x,  dxb = dxa + 1.0f;
                const float bya = g0.w * dya, byb = g0.w * dyb;
                const float cya = (g1.x * dya) * dya, cyb = (g1.x * dyb) * dyb;
                const float axa = (g0.z * dxa) * dxa, axb = (g0.z * dxb) * dxb;
                const unsigned rgbits = __float_as_uint(g1.z);
                __half2 h; __builtin_memcpy(&h, &rgbits, 4);
                const float2 rg = __half22float2(h);
                const float qv[4] = { fmaf(dxa, bya, axa + cya),
                                      fmaf(dxa, byb, axa + cyb),
                                      fmaf(dxb, bya, axb + cya),
                                      fmaf(dxb, byb, axb + cyb) };
                #pragma unroll
                for (int k = 0; k < 4; ++k) {
                    const float a  = g1.y * __builtin_amdgcn_exp2f(qv[k]);
                    const float Tn = Tl[k] * (1.0f - a);
                    const float w  = (gated[k] && Tn >= MINW) ? Tl[k] * a : 0.0f;
                    acc[0][k] = fmaf(w, rg.x, acc[0][k]);
                    acc[1][k] = fmaf(w, rg.y, acc[1][k]);
                    acc[2][k] = fmaf(w, g1.w, acc[2][k]);
                    Tl[k] = Tn;
                }
            }
        }
        const bool mydead = (tid < 256) ? (Tpx < MINW) : true;
        if (__syncthreads_count(mydead) == BLK) break;   // also guards s_g reuse
    }

    // ---- Reduce 16 segment partials per pixel via s_P, one channel at a time
    float sum[3];
    #pragma unroll
    for (int c = 0; c < 3; ++c) {
        __syncthreads();
        #pragma unroll
        for (int k = 0; k < 4; ++k) s_P[seg][pxi[k]] = acc[c][k];
        __syncthreads();
        if (tid < 256) {
            float v = 0.0f;
            #pragma unroll
            for (int s = 0; s < NSEG; ++s) v += s_P[s][tid];
            sum[c] = v;
        }
    }
    if (tid < 256) {
        const int x = blockIdx.x * TILE_SZ + (tid >> 4);
        const int y = blockIdx.y * TILE_SZ + (tid & 15);
        const int o = (x * HEIGHT + y) * 3;
        out[o] = sum[0];  out[o + 1] = sum[1];  out[o + 2] = sum[2];
    }
}

extern "C" void kernel_launch(void* const* d_in, const int* in_sizes, int n_in,
                              void* d_out, int out_size, void* d_ws, size_t ws_size,
                              hipStream_t stream) {
    const float* pts  = (const float*)d_in[0];
    const float* icov = (const float*)d_in[1];
    const float* rad  = (const float*)d_in[2];
    const float* cols = (const float*)d_in[3];
    const float* opac = (const float*)d_in[4];
    float* out = (float*)d_out;
    float4* table = (float4*)d_ws;               // 8192*32 B = 256 KB
    float4* bbt   = table + 2 * NG;              // 8192*16 B = 128 KB
    prep_kernel<<<NG / 256, 256, 0, stream>>>(pts, icov, cols, opac, rad, table, bbt);
    dim3 grid(WIDTH / TILE_SZ, HEIGHT / TILE_SZ);
    // Launched TWICE intentionally (idempotent): wall delta vs next round's
    // single launch gives the kernel's true duration (rocprof top-5 is masked
    // by 40 us harness fills).
    raster_kernel<<<grid, dim3(BLK), 0, stream>>>(bbt, table, out);
    raster_kernel<<<grid, dim3(BLK), 0, stream>>>(bbt, table, out);
}

// Round 9
// 78.372 us; speedup vs baseline: 1.2233x; 1.2233x over previous
//
#include <hip/hip_runtime.h>
#include <hip/hip_fp16.h>

#define WIDTH   256
#define HEIGHT  256
#define NG      8192
#define TILE_SZ 16
#define MINW    1e-6f
#define BLK     1024
#define NBATCH  (NG / BLK)      // 8
#define NWAVE   (BLK / 64)      // 16
#define NSEG    16              // depth segments (one per wave)
#define RSZ     512             // gaussians staged per round
#define KC      (-0.72134752044f)   // -0.5 * log2(e)

// ---- Kernel 1: pack per-gaussian params + bbox once
__global__ __launch_bounds__(256) void prep_kernel(
    const float* __restrict__ pts, const float* __restrict__ icov,
    const float* __restrict__ cols, const float* __restrict__ opac,
    const float* __restrict__ rad,
    float4* __restrict__ table, float4* __restrict__ bbt)
{
    const int g = blockIdx.x * 256 + threadIdx.x;
    const float2 p = ((const float2*)pts)[g];
    const float4 ic = ((const float4*)icov)[g];
    const float r  = rad[g];
    const float op = 1.0f / (1.0f + __expf(-opac[g]));
    const __half2 h = __floats2half2_rn(cols[3 * g], cols[3 * g + 1]);
    unsigned rgbits; __builtin_memcpy(&rgbits, &h, 4);
    table[2 * g + 0] = make_float4(p.x, p.y, KC * ic.x, 2.0f * KC * ic.y);
    table[2 * g + 1] = make_float4(KC * ic.w, op, __uint_as_float(rgbits),
                                   cols[3 * g + 2]);
    bbt[g] = make_float4(floorf(p.x - r), ceilf(p.x + r),
                         floorf(p.y - r), ceilf(p.y + r));
}

// ---- Kernel 2: per-tile cull + depth-split composite (1 block per tile)
__global__ __launch_bounds__(BLK, 4) void raster_kernel(
    const float4* __restrict__ bbt,   // [N] bbox
    const float4* __restrict__ table, // [N,2] packed params
    float* __restrict__ out)          // [W,H,3]
{
    __shared__ unsigned long long s_ball[NBATCH * NWAVE];   // 1 KB
    __shared__ int s_pfx[NBATCH * NWAVE];                   // 0.5 KB
    __shared__ __align__(16) char s_pool[32768];            // 32 KB
    unsigned short* s_list = (unsigned short*)s_pool;       // 16 KB ordered ids
    float4* s_g = (float4*)(s_pool + 16384);                // 16 KB staged chunk
    __shared__ float s_P[NSEG][256];                        // 16 KB P / Tin / reduce

    const int tid  = threadIdx.x;
    const int lane = tid & 63;
    const int wave = tid >> 6;
    const int seg  = wave;            // 0..15
    const float tx0 = (float)(blockIdx.x * TILE_SZ);
    const float ty0 = (float)(blockIdx.y * TILE_SZ);
    const float tx1 = tx0 + (float)TILE_SZ;
    const float ty1 = ty0 + (float)TILE_SZ;

    // ---- Phase 1: prefetch all 8 bboxes, then ballot + wave-0 scan
    float4 bb[NBATCH];
    #pragma unroll
    for (int b = 0; b < NBATCH; ++b) bb[b] = bbt[b * BLK + tid];
    unsigned int hitbits = 0;
    #pragma unroll
    for (int b = 0; b < NBATCH; ++b) {
        bool hit = (bb[b].x <= tx1) & (bb[b].y >= tx0)
                 & (bb[b].z <= ty1) & (bb[b].w >= ty0);
        unsigned long long m = __ballot(hit);
        if (lane == 0) s_ball[b * NWAVE + wave] = m;
        if (hit) hitbits |= (1u << b);
    }
    __syncthreads();
    if (wave == 0) {                  // 128-elem inclusive scan in one wave
        int v0 = __popcll(s_ball[lane]);
        int v1 = __popcll(s_ball[64 + lane]);
        #pragma unroll
        for (int d = 1; d < 64; d <<= 1) {
            const int t0 = __shfl_up(v0, d);
            const int t1 = __shfl_up(v1, d);
            if (lane >= d) { v0 += t0; v1 += t1; }
        }
        s_pfx[lane] = v0;
        s_pfx[64 + lane] = v1 + __shfl(v0, 63);
    }
    __syncthreads();
    const int count = s_pfx[127];
    {
        unsigned int hb = hitbits;
        const unsigned long long ltmask = (1ull << lane) - 1ull;
        while (hb) {
            const int b = __ffs(hb) - 1;  hb &= hb - 1;
            const int idx = b * NWAVE + wave;
            const unsigned long long m = s_ball[idx];
            const int bs = idx ? s_pfx[idx - 1] : 0;
            s_list[bs + __popcll(m & ltmask)] = (unsigned short)(b * BLK + tid);
        }
    }
    __syncthreads();

    // ---- Phase 2: 16 depth segments x 64 quads (2x2 px per thread)
    const int q  = tid & 63;
    const int qx = q >> 3, qy = q & 7;
    const float fx = tx0 + (float)(2 * qx);   // pixel A x; B = +1
    const float fy = ty0 + (float)(2 * qy);   // pixel A y; B = +1
    const int p0 = (2 * qx) * 16 + 2 * qy;
    const int pxi[4] = {p0, p0 + 1, p0 + 16, p0 + 17};
    float Tpx = 1.0f;                          // per-pixel T, owner threads (tid<256)
    float acc[3][4];
    #pragma unroll
    for (int c = 0; c < 3; ++c)
        #pragma unroll
        for (int k = 0; k < 4; ++k) acc[c][k] = 0.0f;

    for (int base = 0; base < count; base += RSZ) {
        const int n = min(RSZ, count - base);
        if (tid < n) {
            const int g = s_list[base + tid];
            s_g[tid * 2 + 0] = table[2 * g + 0];
            s_g[tid * 2 + 1] = table[2 * g + 1];
        }
        __syncthreads();

        const int L  = (n + NSEG - 1) >> 4;
        const int i0 = seg * L;
        const int i1 = min(i0 + L, n);

        float P[4] = {1.f, 1.f, 1.f, 1.f};
        float l[3][4];
        #pragma unroll
        for (int c = 0; c < 3; ++c)
            #pragma unroll
            for (int k = 0; k < 4; ++k) l[c][k] = 0.0f;

        #pragma unroll 2
        for (int i = i0; i < i1; ++i) {
            const float4 g0 = s_g[i * 2 + 0];
            const float4 g1 = s_g[i * 2 + 1];
            const float dya = fy - g0.y,  dyb = dya + 1.0f;
            const float dxa = fx - g0.x,  dxb = dxa + 1.0f;
            const float bya = g0.w * dya, byb = g0.w * dyb;
            const float cya = (g1.x * dya) * dya, cyb = (g1.x * dyb) * dyb;
            const float axa = (g0.z * dxa) * dxa, axb = (g0.z * dxb) * dxb;
            const unsigned rgbits = __float_as_uint(g1.z);
            __half2 h; __builtin_memcpy(&h, &rgbits, 4);
            const float2 rg = __half22float2(h);
            const float qv[4] = { fmaf(dxa, bya, axa + cya),
                                  fmaf(dxa, byb, axa + cyb),
                                  fmaf(dxb, bya, axb + cya),
                                  fmaf(dxb, byb, axb + cyb) };
            #pragma unroll
            for (int k = 0; k < 4; ++k) {
                const float a = g1.y * __builtin_amdgcn_exp2f(qv[k]);
                const float w = P[k] * a;
                l[0][k] = fmaf(w, rg.x, l[0][k]);
                l[1][k] = fmaf(w, rg.y, l[1][k]);
                l[2][k] = fmaf(w, g1.w, l[2][k]);
                P[k] = fmaf(-a, P[k], P[k]);
            }
        }
        #pragma unroll
        for (int k = 0; k < 4; ++k) s_P[seg][pxi[k]] = P[k];
        __syncthreads();

        // owner threads: in-place exclusive-prefix (Tin per segment) over 16 P's
        if (tid < 256) {
            float run = Tpx;
            #pragma unroll
            for (int s = 0; s < NSEG; ++s) {
                const float Pv = s_P[s][tid];
                s_P[s][tid] = run;            // Tin for segment s
                run *= Pv;
            }
            Tpx = run;                        // T after this round
        }
        __syncthreads();

        float Tin[4];
        bool gated[4]; bool anyg = false;
        #pragma unroll
        for (int k = 0; k < 4; ++k) {
            Tin[k] = s_P[seg][pxi[k]];
            const bool alive = (Tin[k] >= MINW);
            gated[k] = alive && (Tin[k] * P[k] < MINW);  // T crossed in this seg
            if (alive && !gated[k]) {
                acc[0][k] = fmaf(Tin[k], l[0][k], acc[0][k]);
                acc[1][k] = fmaf(Tin[k], l[1][k], acc[1][k]);
                acc[2][k] = fmaf(Tin[k], l[2][k], acc[2][k]);
            }
            anyg |= gated[k];
        }
        if (__ballot(anyg) != 0ull) {         // rare: once per pixel lifetime
            float Tl[4] = {Tin[0], Tin[1], Tin[2], Tin[3]};
            for (int i = i0; i < i1; ++i) {
                const float4 g0 = s_g[i * 2 + 0];
                const float4 g1 = s_g[i * 2 + 1];
                const float dya = fy - g0.y,  dyb = dya + 1.0f;
                const float dxa = fx - g0.x,  dxb = dxa + 1.0f;
                const float bya = g0.w * dya, byb = g0.w * dyb;
                const float cya = (g1.x * dya) * dya, cyb = (g1.x * dyb) * dyb;
                const float axa = (g0.z * dxa) * dxa, axb = (g0.z * dxb) * dxb;
                const unsigned rgbits = __float_as_uint(g1.z);
                __half2 h; __builtin_memcpy(&h, &rgbits, 4);
                const float2 rg = __half22float2(h);
                const float qv[4] = { fmaf(dxa, bya, axa + cya),
                                      fmaf(dxa, byb, axa + cyb),
                                      fmaf(dxb, bya, axb + cya),
                                      fmaf(dxb, byb, axb + cyb) };
                #pragma unroll
                for (int k = 0; k < 4; ++k) {
                    const float a  = g1.y * __builtin_amdgcn_exp2f(qv[k]);
                    const float Tn = Tl[k] * (1.0f - a);
                    const float w  = (gated[k] && Tn >= MINW) ? Tl[k] * a : 0.0f;
                    acc[0][k] = fmaf(w, rg.x, acc[0][k]);
                    acc[1][k] = fmaf(w, rg.y, acc[1][k]);
                    acc[2][k] = fmaf(w, g1.w, acc[2][k]);
                    Tl[k] = Tn;
                }
            }
        }
        const bool mydead = (tid < 256) ? (Tpx < MINW) : true;
        if (__syncthreads_count(mydead) == BLK) break;   // also guards s_g reuse
    }

    // ---- Reduce 16 segment partials per pixel via s_P, one channel at a time
    float sum[3];
    #pragma unroll
    for (int c = 0; c < 3; ++c) {
        __syncthreads();
        #pragma unroll
        for (int k = 0; k < 4; ++k) s_P[seg][pxi[k]] = acc[c][k];
        __syncthreads();
        if (tid < 256) {
            float v = 0.0f;
            #pragma unroll
            for (int s = 0; s < NSEG; ++s) v += s_P[s][tid];
            sum[c] = v;
        }
    }
    if (tid < 256) {
        const int x = blockIdx.x * TILE_SZ + (tid >> 4);
        const int y = blockIdx.y * TILE_SZ + (tid & 15);
        const int o = (x * HEIGHT + y) * 3;
        out[o] = sum[0];  out[o + 1] = sum[1];  out[o + 2] = sum[2];
    }
}

extern "C" void kernel_launch(void* const* d_in, const int* in_sizes, int n_in,
                              void* d_out, int out_size, void* d_ws, size_t ws_size,
                              hipStream_t stream) {
    const float* pts  = (const float*)d_in[0];
    const float* icov = (const float*)d_in[1];
    const float* rad  = (const float*)d_in[2];
    const float* cols = (const float*)d_in[3];
    const float* opac = (const float*)d_in[4];
    float* out = (float*)d_out;
    float4* table = (float4*)d_ws;               // 8192*32 B = 256 KB
    float4* bbt   = table + 2 * NG;              // 8192*16 B = 128 KB
    prep_kernel<<<NG / 256, 256, 0, stream>>>(pts, icov, cols, opac, rad, table, bbt);
    dim3 grid(WIDTH / TILE_SZ, HEIGHT / TILE_SZ);
    // SINGLE launch this round: K = wall_R8(2-launch) - wall_R9(this), exact.
    raster_kernel<<<grid, dim3(BLK), 0, stream>>>(bbt, table, out);
}

// Round 10
// 77.920 us; speedup vs baseline: 1.2304x; 1.0058x over previous
//
#include <hip/hip_runtime.h>
#include <hip/hip_fp16.h>

#define WIDTH   256
#define HEIGHT  256
#define NG      8192
#define TILE_SZ 16
#define MINW    1e-6f
#define BLK     1024
#define NBATCH  (NG / BLK)      // 8
#define NWAVE   (BLK / 64)      // 16
#define NSEG    16              // depth segments (one per wave)
#define PXB     128             // pixels per block (8x16 half-tile)
#define RSZ     512             // gaussians staged per round
#define KC      (-0.72134752044f)   // -0.5 * log2(e)

// Single fused kernel: cull + pack + depth-split composite.
// 2 blocks per tile (x-halves) -> 512 blocks -> 2 blocks/CU -> 8 waves/SIMD.
__global__ __launch_bounds__(BLK, 8) void raster_kernel(
    const float* __restrict__ pts,    // [N,2]
    const float* __restrict__ icov,   // [N,2,2]
    const float* __restrict__ rad,    // [N]
    const float* __restrict__ cols,   // [N,3]
    const float* __restrict__ opac,   // [N] logits
    float* __restrict__ out)          // [W,H,3]
{
    __shared__ unsigned long long s_ball[NBATCH * NWAVE];   // 1 KB
    __shared__ int s_pfx[NBATCH * NWAVE];                   // 0.5 KB
    __shared__ __align__(16) char s_pool[32768];            // 32 KB
    unsigned short* s_list = (unsigned short*)s_pool;       // 16 KB ordered ids
    float4* s_g = (float4*)(s_pool + 16384);                // 16 KB staged chunk
    float*  s_red = (float*)s_pool;                         // 24 KB (after loop)
    __shared__ float s_P[NSEG][PXB];                        // 8 KB seg products

    const int tid  = threadIdx.x;
    const int lane = tid & 63;
    const int wave = tid >> 6;
    const int seg  = wave;            // 0..15
    const float tx0 = (float)(blockIdx.x * TILE_SZ);
    const float ty0 = (float)(blockIdx.y * TILE_SZ);
    const float tx1 = tx0 + (float)TILE_SZ;
    const float ty1 = ty0 + (float)TILE_SZ;

    // ---- Phase 1: bbox hit test per batch (tile-granular, same as reference)
    unsigned int hitbits = 0;
    #pragma unroll
    for (int b = 0; b < NBATCH; ++b) {
        const int g = b * BLK + tid;
        const float2 p = ((const float2*)pts)[g];
        const float  r = rad[g];
        bool hit = (floorf(p.x - r) <= tx1) & (ceilf(p.x + r) >= tx0)
                 & (floorf(p.y - r) <= ty1) & (ceilf(p.y + r) >= ty0);
        unsigned long long m = __ballot(hit);
        if (lane == 0) s_ball[b * NWAVE + wave] = m;
        if (hit) hitbits |= (1u << b);
    }
    __syncthreads();
    if (wave == 0) {                  // 128-elem inclusive scan in one wave
        int v0 = __popcll(s_ball[lane]);
        int v1 = __popcll(s_ball[64 + lane]);
        #pragma unroll
        for (int d = 1; d < 64; d <<= 1) {
            const int t0 = __shfl_up(v0, d);
            const int t1 = __shfl_up(v1, d);
            if (lane >= d) { v0 += t0; v1 += t1; }
        }
        s_pfx[lane] = v0;
        s_pfx[64 + lane] = v1 + __shfl(v0, 63);
    }
    __syncthreads();
    const int count = s_pfx[127];
    {
        unsigned int hb = hitbits;
        const unsigned long long ltmask = (1ull << lane) - 1ull;
        while (hb) {
            const int b = __ffs(hb) - 1;  hb &= hb - 1;
            const int idx = b * NWAVE + wave;
            const unsigned long long m = s_ball[idx];
            const int bs = idx ? s_pfx[idx - 1] : 0;
            s_list[bs + __popcll(m & ltmask)] = (unsigned short)(b * BLK + tid);
        }
    }
    __syncthreads();

    // ---- Phase 2: 16 depth segments x 64 y-pairs (2 px/thread, shared x)
    const int pr = tid & 63;          // pair id: xl = pr>>3 (0..7), yp = pr&7
    const int xl = pr >> 3, yp = pr & 7;
    const float fx  = tx0 + (float)(blockIdx.z * 8 + xl);
    const float fyA = ty0 + (float)(2 * yp);  // pixel B y = +1
    const int pA = xl * 16 + 2 * yp;          // local pixel ids (x-major)
    const int pxi[2] = {pA, pA + 1};
    float Tpx = 1.0f;                 // per-pixel T, owner threads (tid<128)
    float acc[3][2];
    #pragma unroll
    for (int c = 0; c < 3; ++c) { acc[c][0] = 0.0f; acc[c][1] = 0.0f; }

    for (int base = 0; base < count; base += RSZ) {
        const int n = min(RSZ, count - base);
        if (tid < n) {                // inline pack (was prep_kernel)
            const int g = s_list[base + tid];
            const float2 p = ((const float2*)pts)[g];
            const float4 ic = ((const float4*)icov)[g];
            const float op = 1.0f / (1.0f + __expf(-opac[g]));
            const __half2 h = __floats2half2_rn(cols[3 * g], cols[3 * g + 1]);
            unsigned rgbits; __builtin_memcpy(&rgbits, &h, 4);
            s_g[tid * 2 + 0] = make_float4(p.x, p.y, KC * ic.x, 2.0f * KC * ic.y);
            s_g[tid * 2 + 1] = make_float4(KC * ic.w, op, __uint_as_float(rgbits),
                                           cols[3 * g + 2]);
        }
        __syncthreads();

        const int L  = (n + NSEG - 1) >> 4;
        const int i0 = seg * L;
        const int i1 = min(i0 + L, n);

        float P[2] = {1.f, 1.f};
        float l[3][2];
        #pragma unroll
        for (int c = 0; c < 3; ++c) { l[c][0] = 0.0f; l[c][1] = 0.0f; }

        #pragma unroll 2
        for (int i = i0; i < i1; ++i) {
            const float4 g0 = s_g[i * 2 + 0];
            const float4 g1 = s_g[i * 2 + 1];
            const float dx  = fx - g0.x;               // shared between the 2 px
            const float axx = (g0.z * dx) * dx;
            const float bdx = g0.w * dx;
            const float dyA = fyA - g0.y, dyB = dyA + 1.0f;
            const float qv[2] = { fmaf(dyA, fmaf(g1.x, dyA, bdx), axx),
                                  fmaf(dyB, fmaf(g1.x, dyB, bdx), axx) };
            const unsigned rgbits = __float_as_uint(g1.z);
            __half2 h; __builtin_memcpy(&h, &rgbits, 4);
            const float2 rg = __half22float2(h);
            #pragma unroll
            for (int k = 0; k < 2; ++k) {
                const float a = g1.y * __builtin_amdgcn_exp2f(qv[k]);
                const float w = P[k] * a;
                l[0][k] = fmaf(w, rg.x, l[0][k]);
                l[1][k] = fmaf(w, rg.y, l[1][k]);
                l[2][k] = fmaf(w, g1.w, l[2][k]);
                P[k] = fmaf(-a, P[k], P[k]);
            }
        }
        s_P[seg][pxi[0]] = P[0];
        s_P[seg][pxi[1]] = P[1];
        __syncthreads();

        // owner threads: in-place exclusive prefix (Tin per segment) over 16 P's
        if (tid < PXB) {
            float run = Tpx;
            #pragma unroll
            for (int s = 0; s < NSEG; ++s) {
                const float Pv = s_P[s][tid];
                s_P[s][tid] = run;            // Tin for segment s
                run *= Pv;
            }
            Tpx = run;
        }
        __syncthreads();

        float Tin[2];
        bool gated[2]; bool anyg = false;
        #pragma unroll
        for (int k = 0; k < 2; ++k) {
            Tin[k] = s_P[seg][pxi[k]];
            const bool alive = (Tin[k] >= MINW);
            gated[k] = alive && (Tin[k] * P[k] < MINW);  // T crossed in this seg
            if (alive && !gated[k]) {
                acc[0][k] = fmaf(Tin[k], l[0][k], acc[0][k]);
                acc[1][k] = fmaf(Tin[k], l[1][k], acc[1][k]);
                acc[2][k] = fmaf(Tin[k], l[2][k], acc[2][k]);
            }
            anyg |= gated[k];
        }
        if (__ballot(anyg) != 0ull) {         // rare: once per pixel lifetime
            float Tl[2] = {Tin[0], Tin[1]};
            for (int i = i0; i < i1; ++i) {
                const float4 g0 = s_g[i * 2 + 0];
                const float4 g1 = s_g[i * 2 + 1];
                const float dx  = fx - g0.x;
                const float axx = (g0.z * dx) * dx;
                const float bdx = g0.w * dx;
                const float dyA = fyA - g0.y, dyB = dyA + 1.0f;
                const float qv[2] = { fmaf(dyA, fmaf(g1.x, dyA, bdx), axx),
                                      fmaf(dyB, fmaf(g1.x, dyB, bdx), axx) };
                const unsigned rgbits = __float_as_uint(g1.z);
                __half2 h; __builtin_memcpy(&h, &rgbits, 4);
                const float2 rg = __half22float2(h);
                #pragma unroll
                for (int k = 0; k < 2; ++k) {
                    const float a  = g1.y * __builtin_amdgcn_exp2f(qv[k]);
                    const float Tn = Tl[k] * (1.0f - a);
                    const float w  = (gated[k] && Tn >= MINW) ? Tl[k] * a : 0.0f;
                    acc[0][k] = fmaf(w, rg.x, acc[0][k]);
                    acc[1][k] = fmaf(w, rg.y, acc[1][k]);
                    acc[2][k] = fmaf(w, g1.w, acc[2][k]);
                    Tl[k] = Tn;
                }
            }
        }
        const bool mydead = (tid < PXB) ? (Tpx < MINW) : true;
        if (__syncthreads_count(mydead) == BLK) break;   // also guards s_g reuse
    }
    // loop always exits via a barrier => s_list/s_g dead, alias as s_red

    // ---- Reduce 16 segment partials per pixel, store this block's 128 px
    #pragma unroll
    for (int k = 0; k < 2; ++k) {
        s_red[(seg * PXB + pxi[k]) * 3 + 0] = acc[0][k];
        s_red[(seg * PXB + pxi[k]) * 3 + 1] = acc[1][k];
        s_red[(seg * PXB + pxi[k]) * 3 + 2] = acc[2][k];
    }
    __syncthreads();
    if (tid < PXB * 3) {
        const int p  = tid / 3;
        const int ch = tid - 3 * p;
        float v = 0.0f;
        #pragma unroll
        for (int s = 0; s < NSEG; ++s) v += s_red[(s * PXB + p) * 3 + ch];
        const int x = blockIdx.x * TILE_SZ + blockIdx.z * 8 + (p >> 4);
        const int y = blockIdx.y * TILE_SZ + (p & 15);
        out[(x * HEIGHT + y) * 3 + ch] = v;
    }
}

extern "C" void kernel_launch(void* const* d_in, const int* in_sizes, int n_in,
                              void* d_out, int out_size, void* d_ws, size_t ws_size,
                              hipStream_t stream) {
    const float* pts  = (const float*)d_in[0];
    const float* icov = (const float*)d_in[1];
    const float* rad  = (const float*)d_in[2];
    const float* cols = (const float*)d_in[3];
    const float* opac = (const float*)d_in[4];
    float* out = (float*)d_out;
    dim3 grid(WIDTH / TILE_SZ, HEIGHT / TILE_SZ, 2);   // 2 blocks/tile (x-halves)
    raster_kernel<<<grid, dim3(BLK), 0, stream>>>(pts, icov, rad, cols, opac, out);
}